// Round 11
// baseline (455.028 us; speedup 1.0000x reference)
//
#include <hip/hip_runtime.h>

constexpr int N   = 50000;
constexpr int E   = 500000;
constexpr int HID = 128;
constexpr int NH  = 8;
constexpr int ED  = 32;
constexpr int EGD = 64;
constexpr int NB  = (N + 255) / 256;

typedef short  bf16x8 __attribute__((ext_vector_type(8)));
typedef float  f32x4  __attribute__((ext_vector_type(4)));

// tanh-form gelu: v * sigmoid(1.5957691*v + 0.0713548*v^3); max |err| vs erf ~3e-4
__device__ __forceinline__ float gelu_f(float v) {
    float u = v * v;
    float a = v * fmaf(u, -0.07135481283f, -1.5957691216f);
    float e = __expf(a);
    return v * __builtin_amdgcn_rcpf(1.f + e);
}
__device__ __forceinline__ float sigm_f(float v) {
    float e = __expf(-v);
    return __builtin_amdgcn_rcpf(1.f + e);
}
// NATIVE bf16 conversion (RTNE) — pure C++ cast, no inline asm (R4 lesson:
// asm in k_edge perturbs regalloc into spill).  The compiler pattern-matches
// standard casts into hardware v_cvt_pk_bf16_f32 (guide m240); the old
// 4-instr bit-trick rounding was ~1200 VALU/thread in k_edge (~25% of VALU).
__device__ __forceinline__ unsigned short f2bf(float f) {
    return __builtin_bit_cast(unsigned short, static_cast<__bf16>(f));
}
__device__ __forceinline__ unsigned int pk2bf(float lo, float hi) {
    return (unsigned int)f2bf(lo) | ((unsigned int)f2bf(hi) << 16);
}
__device__ __forceinline__ float dot2(unsigned int a, unsigned int b) {
    float al = __uint_as_float(a << 16), ah = __uint_as_float(a & 0xffff0000u);
    float bl = __uint_as_float(b << 16), bh = __uint_as_float(b & 0xffff0000u);
    return al * bl + ah * bh;
}

// ---------------------------------------------------------------------------
// Weight conversion: all weight matrices -> bf16 MFMA B-fragment order.
// ---------------------------------------------------------------------------
__global__ __launch_bounds__(256) void k_cvt(
    const float* __restrict__ Wq, const float* __restrict__ Wk,
    const float* __restrict__ Wv, const float* __restrict__ Wo,
    const float* __restrict__ fw1, const float* __restrict__ fw2,
    const float* __restrict__ ea_w1, const float* __restrict__ ea_w2,
    const float* __restrict__ eg_w1, const float* __restrict__ eg_w2,
    unsigned short* __restrict__ dst)
{
    int f = blockIdx.x * 256 + threadIdx.x;
    if (f >= 18048) return;
    const float* W; int KT, srcN, base;
    if      (f < 2048)  { W = Wq;    KT = 4; srcN = 128; base = 0; }
    else if (f < 4096)  { W = Wk;    KT = 4; srcN = 128; base = 2048; }
    else if (f < 6144)  { W = Wv;    KT = 4; srcN = 128; base = 4096; }
    else if (f < 8192)  { W = Wo;    KT = 4; srcN = 128; base = 6144; }
    else if (f < 12288) { W = fw1;   KT = 4; srcN = 256; base = 8192; }
    else if (f < 16384) { W = fw2;   KT = 8; srcN = 128; base = 12288; }
    else if (f < 16640) { W = ea_w1; KT = 1; srcN = 64;  base = 16384; }
    else if (f < 16768) { W = ea_w2; KT = 2; srcN = 8;   base = 16640; }
    else if (f < 17024) { W = eg_w1; KT = 1; srcN = 64;  base = 16768; }
    else                { W = eg_w2; KT = 2; srcN = 128; base = 17024; }
    int fl = f - base, lane = fl & 63, t = fl >> 6;
    int ks = t % KT, nt = t / KT;
    int n  = nt * 16 + (lane & 15);
    int k0 = ks * 32 + (lane >> 4) * 8;
    union { unsigned short u[8]; uint4 v; } o;
#pragma unroll
    for (int j = 0; j < 8; j++)
        o.u[j] = (n < srcN) ? f2bf(W[(size_t)(k0 + j) * srcN + n]) : (unsigned short)0;
    *(uint4*)(dst + (size_t)f * 8) = o.v;
}

// ---------------------------------------------------------------------------
// LN1 + QKV via MFMA -> bf16 Q/K/V.
// COLUMN-SPLIT 4-wave blocks: 16 nodes / 256 threads (R10-verified).
// ---------------------------------------------------------------------------
__global__ __launch_bounds__(256) void k_ln_qkv_mfma(
    const float* __restrict__ x, const float* __restrict__ g1, const float* __restrict__ b1,
    const unsigned short* __restrict__ wqkv,
    unsigned short* __restrict__ Q, unsigned short* __restrict__ K, unsigned short* __restrict__ V)
{
    __shared__ unsigned short xn_lds[16 * 128];   // 4KB
    const int tid = threadIdx.x;
    const int nodeBase = blockIdx.x * 16;         // N % 16 == 0: no bounds checks

    // Phase 0: LN staging — 16 threads per node, each handles 8 cols
    {
        int nl = tid >> 4, q = tid & 15;
        const float4* xp = (const float4*)(x + (size_t)(nodeBase + nl) * HID + q * 8);
        float4 t0 = xp[0], t1 = xp[1];
        float v[8] = {t0.x, t0.y, t0.z, t0.w, t1.x, t1.y, t1.z, t1.w};
        float s = 0.f, ss = 0.f;
#pragma unroll
        for (int i = 0; i < 8; i++) { s += v[i]; ss += v[i] * v[i]; }
        s += __shfl_xor(s, 1); ss += __shfl_xor(ss, 1);
        s += __shfl_xor(s, 2); ss += __shfl_xor(ss, 2);
        s += __shfl_xor(s, 4); ss += __shfl_xor(ss, 4);
        s += __shfl_xor(s, 8); ss += __shfl_xor(ss, 8);
        float mean = s * (1.f / HID);
        float ri = rsqrtf(ss * (1.f / HID) - mean * mean + 1e-5f);
        union { unsigned short u[8]; uint4 v4; } o;
#pragma unroll
        for (int c = 0; c < 8; c++) {
            int col = q * 8 + c;
            o.u[c] = f2bf((v[c] - mean) * ri * g1[col] + b1[col]);
        }
        *(uint4*)&xn_lds[nl * 128 + (q ^ nl) * 8] = o.v4;
    }
    __syncthreads();

    // Phase 1: wave wv computes nt = 6*wv .. 6*wv+5 (swapped operands:
    // C[col][node], thread owns 4 consecutive cols of node lm)
    const int wv = tid >> 6, lane = tid & 63;
    const int lm = lane & 15, kb = lane >> 4, rowq = kb * 4;
    bf16x8 af[4];
#pragma unroll
    for (int ks = 0; ks < 4; ks++)
        af[ks] = *(const bf16x8*)&xn_lds[lm * 128 + ((ks * 4 + kb) ^ lm) * 8];

    const int node = nodeBase + lm;
#pragma unroll
    for (int u = 0; u < 6; u++) {
        int nt = 6 * wv + u;
        f32x4 c = {0.f, 0.f, 0.f, 0.f};
#pragma unroll
        for (int ks = 0; ks < 4; ks++)
            c = __builtin_amdgcn_mfma_f32_16x16x32_bf16(
                    *(const bf16x8*)&wqkv[((size_t)(nt * 4 + ks) * 64 + lane) * 8],
                    af[ks], c, 0, 0, 0);
        unsigned short* O = (nt < 8) ? Q : ((nt < 16) ? K : V);
        uint2 o = make_uint2(pk2bf(c[0], c[1]), pk2bf(c[2], c[3]));
        *(uint2*)(O + (size_t)node * HID + (nt & 7) * 16 + rowq) = o;
    }
}

// ---------------------------------------------------------------------------
// Sorting: histogram -> scan -> scatter (esd = {src, dst, perm, 0} records)
// ---------------------------------------------------------------------------
__global__ __launch_bounds__(256) void k_hist(const int* __restrict__ ei, int* __restrict__ cnt) {
    int e = blockIdx.x * 256 + threadIdx.x;
    if (e < E) atomicAdd(&cnt[ei[E + e]], 1);
}

__global__ __launch_bounds__(256) void k_bsum(const int* __restrict__ cnt, int* __restrict__ bsum) {
    int i = blockIdx.x * 256 + threadIdx.x;
    int v = (i < N) ? cnt[i] : 0;
#pragma unroll
    for (int m = 1; m < 64; m <<= 1) v += __shfl_xor(v, m);
    __shared__ int ws4[4];
    if ((threadIdx.x & 63) == 0) ws4[threadIdx.x >> 6] = v;
    __syncthreads();
    if (threadIdx.x == 0) bsum[blockIdx.x] = ws4[0] + ws4[1] + ws4[2] + ws4[3];
}

__global__ __launch_bounds__(256) void k_scan_b(const int* __restrict__ bsum, int* __restrict__ boff) {
    __shared__ int s[256];
    int t = threadIdx.x;
    int v = (t < NB) ? bsum[t] : 0;
    s[t] = v; __syncthreads();
    for (int off = 1; off < 256; off <<= 1) {
        int add = (t >= off) ? s[t - off] : 0;
        __syncthreads();
        s[t] += add;
        __syncthreads();
    }
    if (t < NB) boff[t] = s[t] - v;
}

__global__ __launch_bounds__(256) void k_scan_final(
    const int* __restrict__ cnt, const int* __restrict__ boff,
    int* __restrict__ starts, int* __restrict__ cursor)
{
    __shared__ int s[256];
    int t = threadIdx.x, i = blockIdx.x * 256 + t;
    int v = (i < N) ? cnt[i] : 0;
    s[t] = v; __syncthreads();
    for (int off = 1; off < 256; off <<= 1) {
        int add = (t >= off) ? s[t - off] : 0;
        __syncthreads();
        s[t] += add;
        __syncthreads();
    }
    int ex = boff[blockIdx.x] + s[t] - v;
    if (i < N) {
        starts[i] = ex;
        cursor[i] = ex;
        if (i == N - 1) starts[N] = ex + v;
    }
}

__global__ __launch_bounds__(256) void k_scatter(
    const int* __restrict__ ei, int* __restrict__ cursor, uint4* __restrict__ esd)
{
    int e = blockIdx.x * 256 + threadIdx.x;
    if (e < E) {
        int src = ei[e], dst = ei[E + e];
        int p = atomicAdd(&cursor[dst], 1);
        esd[p] = make_uint4((unsigned)src, (unsigned)dst, (unsigned)e, 0u);
    }
}

// ---------------------------------------------------------------------------
// Fused edge kernel (R8 structure: 108 VGPR, zero spill, 136us).
// REGALLOC DISCIPLINE: plain __launch_bounds__(256), NO waves-arg, NO inline
// asm (R3/R4/R7 regressions).  THIS ROUND: f2bf -> native __bf16 cast (pure
// C++; cuts the ~1200-VALU/thread bit-trick rounding bucket) + 2-chunk
// launch for rocprof visibility of the ~317us non-edge pool.
// ---------------------------------------------------------------------------
__global__ __launch_bounds__(256) void k_edge(
    const int bOff,
    const float* __restrict__ edge_attr, const uint4* __restrict__ esd,
    const unsigned short* __restrict__ Qb, const unsigned short* __restrict__ Kb,
    const unsigned short* __restrict__ Vb,
    const unsigned short* __restrict__ w1ea, const float* __restrict__ b1ea,
    const unsigned short* __restrict__ w2ea, const float* __restrict__ b2ea,
    const unsigned short* __restrict__ w1eg, const float* __restrict__ b1eg,
    const unsigned short* __restrict__ w2eg, const float* __restrict__ b2eg,
    float* __restrict__ logit_s, unsigned int* __restrict__ gv)
{
    __shared__ unsigned short ea_lds[256 * 32];      // 16KB: edge_attr bf16, later st16 floats
    __shared__ unsigned short sc_lds[4 * 16 * 64];   // 8KB: per-wave GEMM1->GEMM2 scratch
    __shared__ int perm_lds[256];
    __shared__ int src_lds[256];
    float* st16 = (float*)ea_lds;

    const int tid   = threadIdx.x;
    const int jBase = (blockIdx.x + bOff) * 256;
    const int lane  = tid & 63;
    const int wv    = tid >> 6;
    const int wBase = wv * 64;
    const int lm    = lane & 15;
    const int kb    = lane >> 4;
    const int rowq  = kb * 4;

    const int j  = jBase + tid;
    const int jj = (j < E) ? j : E - 1;
    const uint4 r4 = esd[jj];            // (src, dst, perm, 0)
    {
        perm_lds[tid] = (int)r4.z;
        src_lds[tid]  = (int)r4.x;
    }
    __syncthreads();

    // stage edge_attr[perm[j]] -> bf16 swizzled LDS (packed 8B ds_write)
#pragma unroll
    for (int it = 0; it < 8; it++) {
        int idx = it * 256 + tid;
        int el = idx >> 3, c = (idx & 7) * 4;
        int ge = perm_lds[el];
        float4 v = *(const float4*)(edge_attr + (size_t)ge * ED + c);
        int g = ((c >> 3) ^ (el & 3));
        *(uint2*)&ea_lds[el * 32 + g * 8 + (c & 7)] =
            make_uint2(pk2bf(v.x, v.y), pk2bf(v.z, v.w));
    }
    __syncthreads();
    // everything below is wave-private (own 64 rows of ea_lds / own scratch)

    unsigned short* sc = &sc_lds[wv * 1024];  // [16 edges][64 hid], XOR-swizzled

#pragma unroll 1
    for (int et = 0; et < 4; et++) {
        const int am = wBase + et * 16 + lm;
        const bf16x8 a1 = *(const bf16x8*)&ea_lds[am * 32 + (kb ^ (am & 3)) * 8];

        // ---- ea GEMM1 -> scratch ----
        {
            f32x4 acc[4];
#pragma unroll
            for (int nt = 0; nt < 4; nt++) {
                f32x4 z = {0.f, 0.f, 0.f, 0.f};
                acc[nt] = __builtin_amdgcn_mfma_f32_16x16x32_bf16(
                    a1, *(const bf16x8*)&w1ea[(nt * 64 + lane) * 8], z, 0, 0, 0);
            }
#pragma unroll
            for (int nt = 0; nt < 4; nt++) {
                float bias = b1ea[nt * 16 + lm];
#pragma unroll
                for (int r = 0; r < 4; r++) {
                    int el = rowq + r;
                    int kg = nt * 2 + (lm >> 3);
                    sc[el * 64 + ((kg ^ (el & 7)) * 8) + (lm & 7)] =
                        f2bf(gelu_f(acc[nt][r] + bias));
                }
            }
        }
        // ---- ea GEMM2 -> st16 (same-wave rows; LDS pipe is in-order per wave) ----
        {
            bf16x8 f0 = *(const bf16x8*)&sc[lm * 64 + ((kb ^ (lm & 7)) * 8)];
            bf16x8 f1 = *(const bf16x8*)&sc[lm * 64 + (((4 + kb) ^ (lm & 7)) * 8)];
            float bias = b2ea[lm & 7];
            f32x4 acc = {bias, bias, bias, bias};
            acc = __builtin_amdgcn_mfma_f32_16x16x32_bf16(
                f0, *(const bf16x8*)&w2ea[(0 * 64 + lane) * 8], acc, 0, 0, 0);
            acc = __builtin_amdgcn_mfma_f32_16x16x32_bf16(
                f1, *(const bf16x8*)&w2ea[(1 * 64 + lane) * 8], acc, 0, 0, 0);
            if (lm < 8) {
#pragma unroll
                for (int r = 0; r < 4; r++)
                    st16[(wBase + et * 16 + rowq + r) * 16 + lm] = acc[r];
            }
        }
        // ---- eg GEMM1 (reuse a1) -> scratch (overwrite own rows) ----
        {
            f32x4 acc[4];
#pragma unroll
            for (int nt = 0; nt < 4; nt++) {
                f32x4 z = {0.f, 0.f, 0.f, 0.f};
                acc[nt] = __builtin_amdgcn_mfma_f32_16x16x32_bf16(
                    a1, *(const bf16x8*)&w1eg[(nt * 64 + lane) * 8], z, 0, 0, 0);
            }
#pragma unroll
            for (int nt = 0; nt < 4; nt++) {
                float bias = b1eg[nt * 16 + lm];
#pragma unroll
                for (int r = 0; r < 4; r++) {
                    int el = rowq + r;
                    int kg = nt * 2 + (lm >> 3);
                    sc[el * 64 + ((kg ^ (el & 7)) * 8) + (lm & 7)] =
                        f2bf(gelu_f(acc[nt][r] + bias));
                }
            }
        }
        // ---- eg GEMM2 swapped: C[out_dim][edge]; thread -> edge et*16+lm,
        //      dims mt*16 + kb*4 .. +3 (consecutive) ----
        {
            bf16x8 h0 = *(const bf16x8*)&sc[lm * 64 + ((kb ^ (lm & 7)) * 8)];
            bf16x8 h1 = *(const bf16x8*)&sc[lm * 64 + (((4 + kb) ^ (lm & 7)) * 8)];
            const int e   = jBase + wBase + et * 16 + lm;
            const int src = src_lds[wBase + et * 16 + lm];
            const unsigned short* vrow = Vb + (size_t)src * HID;
            const bool ok = (e < E);
            unsigned int* gvo = gv + (size_t)e * 64 + kb * 2;
#pragma unroll
            for (int mt = 0; mt < 8; mt++) {
                float4 b4 = *(const float4*)&b2eg[mt * 16 + rowq];
                f32x4 acc = {b4.x, b4.y, b4.z, b4.w};
                acc = __builtin_amdgcn_mfma_f32_16x16x32_bf16(
                    *(const bf16x8*)&w2eg[((mt * 2 + 0) * 64 + lane) * 8], h0, acc, 0, 0, 0);
                acc = __builtin_amdgcn_mfma_f32_16x16x32_bf16(
                    *(const bf16x8*)&w2eg[((mt * 2 + 1) * 64 + lane) * 8], h1, acc, 0, 0, 0);
                uint2 vv = *(const uint2*)(vrow + mt * 16 + rowq);
                float w0 = sigm_f(acc[0]) * __uint_as_float(vv.x << 16);
                float w1 = sigm_f(acc[1]) * __uint_as_float(vv.x & 0xffff0000u);
                float w2 = sigm_f(acc[2]) * __uint_as_float(vv.y << 16);
                float w3 = sigm_f(acc[3]) * __uint_as_float(vv.y & 0xffff0000u);
                uint2 o = make_uint2(pk2bf(w0, w1), pk2bf(w2, w3));
                if (ok) *(uint2*)(gvo + mt * 8) = o;
            }
        }
    }

    // ---- QK logit epilogue: store exp(logit) (clamped) for the aggregator ----
    {
        if (j < E) {
            int src = (int)r4.x, dst = (int)r4.y;
            const uint4* qp = (const uint4*)(Qb + (size_t)dst * HID);
            const uint4* kp = (const uint4*)(Kb + (size_t)src * HID);
            float lg[8];
#pragma unroll
            for (int h = 0; h < 8; h++) {
                float dot = 0.f;
#pragma unroll
                for (int t = 0; t < 2; t++) {
                    uint4 q = qp[h * 2 + t], k4 = kp[h * 2 + t];
                    dot += dot2(q.x, k4.x) + dot2(q.y, k4.y) + dot2(q.z, k4.z) + dot2(q.w, k4.w);
                }
                lg[h] = __expf(fminf(st16[tid * 16 + h] + 0.25f * dot, 80.f));
            }
            float4* op = (float4*)(logit_s + (size_t)j * NH);
            op[0] = make_float4(lg[0], lg[1], lg[2], lg[3]);
            op[1] = make_float4(lg[4], lg[5], lg[6], lg[7]);
        }
    }
}

// ---------------------------------------------------------------------------
// Fused segment softmax + attn * gv aggregation, SINGLE PASS.
// logit_s already holds exp(l) (shift-invariant softmax).
// ---------------------------------------------------------------------------
__global__ __launch_bounds__(256) void k_agg2(
    const int* __restrict__ starts, const unsigned int* __restrict__ gv,
    const float* __restrict__ logit_s, float* __restrict__ agg)
{
    int wave = threadIdx.x >> 6, lane = threadIdx.x & 63;
    int dst = blockIdx.x * 4 + wave;
    if (dst >= N) return;
    int s0 = starts[dst], s1 = starts[dst + 1];
    int head = lane >> 3;
    float ssum = 0.f, ax = 0.f, ay = 0.f;
#pragma unroll 4
    for (int j = s0; j < s1; j++) {
        float e = logit_s[(size_t)j * NH + head];
        unsigned int u = gv[(size_t)j * 64 + lane];
        ssum += e;
        ax += e * __uint_as_float(u << 16);
        ay += e * __uint_as_float(u & 0xffff0000u);
    }
    float rs = __builtin_amdgcn_rcpf(ssum + 1e-10f);
    float2* o = (float2*)(agg + (size_t)dst * HID + lane * 2);
    *o = make_float2(ax * rs, ay * rs);
}

// ---------------------------------------------------------------------------
// Node epilogue via MFMA.  COLUMN-SPLIT 4-wave blocks (R10-verified):
// 16 nodes / 256 threads, each wave 1/4 of every GEMM, 4 barriers.
// ---------------------------------------------------------------------------
__global__ __launch_bounds__(256) void k_node_out_mfma(
    const float* __restrict__ x, const float* __restrict__ gamma, const float* __restrict__ beta,
    const unsigned short* __restrict__ wo_f, const float* __restrict__ bo,
    const float* __restrict__ g2, const float* __restrict__ b2,
    const unsigned short* __restrict__ fw1_f, const float* __restrict__ fb1,
    const unsigned short* __restrict__ fw2_f, const float* __restrict__ fb2,
    const float* __restrict__ agg, float* __restrict__ out)
{
    __shared__ unsigned short a_lds[16 * 128];    // 4KB
    __shared__ unsigned short f1_lds[16 * 256];   // 8KB
    __shared__ float2 sums_lds[16][4];            // 512B: per-node per-wave LN partials
    const int tid = threadIdx.x;
    const int nodeBase = blockIdx.x * 16;         // N % 16 == 0

    // Phase 0: stage agg -> a_lds (one uint4 per thread)
    {
        int nl = tid >> 4, q = tid & 15;
        const float4* ap = (const float4*)(agg + (size_t)(nodeBase + nl) * HID + q * 8);
        float4 t0 = ap[0], t1 = ap[1];
        uint4 o = make_uint4(pk2bf(t0.x, t0.y), pk2bf(t0.z, t0.w),
                             pk2bf(t1.x, t1.y), pk2bf(t1.z, t1.w));
        *(uint4*)&a_lds[nl * 128 + (q ^ nl) * 8] = o;
    }
    __syncthreads();

    const int wv = tid >> 6, lane = tid & 63;
    const int lm = lane & 15, kb = lane >> 4, rowq = kb * 4;

    // Phase 1: Wo GEMM — wave wv handles nt = 2*wv + t
    f32x4 xo[2];
    {
        bf16x8 af[4];
#pragma unroll
        for (int ks = 0; ks < 4; ks++)
            af[ks] = *(const bf16x8*)&a_lds[lm * 128 + ((ks * 4 + kb) ^ lm) * 8];
#pragma unroll
        for (int t = 0; t < 2; t++) {
            int nt = 2 * wv + t;
            f32x4 c = {0.f, 0.f, 0.f, 0.f};
#pragma unroll
            for (int ks = 0; ks < 4; ks++)
                c = __builtin_amdgcn_mfma_f32_16x16x32_bf16(
                        af[ks], *(const bf16x8*)&wo_f[((size_t)(nt * 4 + ks) * 64 + lane) * 8],
                        c, 0, 0, 0);
            xo[t] = c;
        }
    }

    // Phase 2: x1 = x + gamma*(xo+bo) + beta for this wave's 32 cols
    float x1v[2][4];
#pragma unroll
    for (int t = 0; t < 2; t++) {
        int col = (2 * wv + t) * 16 + lm;
        float boc = bo[col];
#pragma unroll
        for (int r = 0; r < 4; r++) {
            size_t idx = (size_t)(nodeBase + rowq + r) * HID + col;
            x1v[t][r] = x[idx] + gamma[idx] * (xo[t][r] + boc) + beta[idx];
        }
    }

    // Phase 3: LN partials -> exchange -> full stats
    {
        float s2[4], q2[4];
#pragma unroll
        for (int r = 0; r < 4; r++) {
            s2[r] = x1v[0][r] + x1v[1][r];
            q2[r] = x1v[0][r] * x1v[0][r] + x1v[1][r] * x1v[1][r];
        }
#pragma unroll
        for (int m = 1; m < 16; m <<= 1)
#pragma unroll
            for (int r = 0; r < 4; r++) { s2[r] += __shfl_xor(s2[r], m); q2[r] += __shfl_xor(q2[r], m); }
        if (lm == 0) {
#pragma unroll
            for (int r = 0; r < 4; r++)
                sums_lds[rowq + r][wv] = make_float2(s2[r], q2[r]);
        }
    }
    __syncthreads();
    float mu4[4], ri4[4];
#pragma unroll
    for (int r = 0; r < 4; r++) {
        float2 p0 = sums_lds[rowq + r][0], p1 = sums_lds[rowq + r][1];
        float2 p2 = sums_lds[rowq + r][2], p3 = sums_lds[rowq + r][3];
        float s = p0.x + p1.x + p2.x + p3.x;
        float q = p0.y + p1.y + p2.y + p3.y;
        float mu = s * (1.f / HID);
        mu4[r] = mu;
        ri4[r] = rsqrtf(q * (1.f / HID) - mu * mu + 1e-5f);
    }

    // Phase 4: xn -> a_lds (this wave's 32 cols)
#pragma unroll
    for (int t = 0; t < 2; t++) {
        int col = (2 * wv + t) * 16 + lm;
        float g2c = g2[col], b2c = b2[col];
#pragma unroll
        for (int r = 0; r < 4; r++) {
            float xn = (x1v[t][r] - mu4[r]) * ri4[r] * g2c + b2c;
            int row = rowq + r;
            int g = col >> 3;
            a_lds[row * 128 + (g ^ row) * 8 + (col & 7)] = f2bf(xn);
        }
    }
    __syncthreads();

    // Phase 5: fw1 — wave wv handles nt = 4*wv .. 4*wv+3 -> f1_lds
    {
        bf16x8 af[4];
#pragma unroll
        for (int ks = 0; ks < 4; ks++)
            af[ks] = *(const bf16x8*)&a_lds[lm * 128 + ((ks * 4 + kb) ^ lm) * 8];
#pragma unroll
        for (int u = 0; u < 4; u++) {
            int nt = 4 * wv + u;
            f32x4 c = {0.f, 0.f, 0.f, 0.f};
#pragma unroll
            for (int ks = 0; ks < 4; ks++)
                c = __builtin_amdgcn_mfma_f32_16x16x32_bf16(
                        af[ks], *(const bf16x8*)&fw1_f[((size_t)(nt * 4 + ks) * 64 + lane) * 8],
                        c, 0, 0, 0);
            int col = nt * 16 + lm;
            float fbc = fb1[col];
#pragma unroll
            for (int r = 0; r < 4; r++) {
                int row = rowq + r;
                int g = col >> 3;
                int phys = (g & 16) | ((g ^ row) & 15);
                f1_lds[row * 256 + phys * 8 + (col & 7)] = f2bf(gelu_f(c[r] + fbc));
            }
        }
    }
    __syncthreads();

    // Phase 6: fw2 — wave wv handles nt = 2*wv + t; residual add; store
    {
        bf16x8 af[8];
#pragma unroll
        for (int ks = 0; ks < 8; ks++) {
            int g = ks * 4 + kb;
            int phys = (g & 16) | ((g ^ lm) & 15);
            af[ks] = *(const bf16x8*)&f1_lds[lm * 256 + phys * 8];
        }
#pragma unroll
        for (int t = 0; t < 2; t++) {
            int nt = 2 * wv + t;
            f32x4 c = {0.f, 0.f, 0.f, 0.f};
#pragma unroll
            for (int ks = 0; ks < 8; ks++)
                c = __builtin_amdgcn_mfma_f32_16x16x32_bf16(
                        af[ks], *(const bf16x8*)&fw2_f[((size_t)(nt * 8 + ks) * 64 + lane) * 8],
                        c, 0, 0, 0);
            int col = nt * 16 + lm;
            float fbc = fb2[col];
#pragma unroll
            for (int r = 0; r < 4; r++) {
                int node = nodeBase + rowq + r;
                out[(size_t)node * HID + col] = x1v[t][r] + c[r] + fbc;
            }
        }
    }
}

// ---------------------------------------------------------------------------
extern "C" void kernel_launch(void* const* d_in, const int* in_sizes, int n_in,
                              void* d_out, int out_size, void* d_ws, size_t ws_size,
                              hipStream_t stream)
{
    const float* x         = (const float*)d_in[0];
    const float* edge_attr = (const float*)d_in[1];
    const float* gamma     = (const float*)d_in[2];
    const float* beta      = (const float*)d_in[3];
    const float* Wq        = (const float*)d_in[4];
    const float* Wk        = (const float*)d_in[5];
    const float* Wv        = (const float*)d_in[6];
    const float* Wo        = (const float*)d_in[7];
    const float* bo        = (const float*)d_in[8];
    const float* ea_w1     = (const float*)d_in[9];
    const float* ea_b1     = (const float*)d_in[10];
    const float* ea_w2     = (const float*)d_in[11];
    const float* ea_b2     = (const float*)d_in[12];
    const float* eg_w1     = (const float*)d_in[13];
    const float* eg_b1     = (const float*)d_in[14];
    const float* eg_w2     = (const float*)d_in[15];
    const float* eg_b2     = (const float*)d_in[16];
    const float* ln1_g     = (const float*)d_in[17];
    const float* ln1_b     = (const float*)d_in[18];
    const float* ln2_g     = (const float*)d_in[19];
    const float* ln2_b     = (const float*)d_in[20];
    const float* fw1       = (const float*)d_in[21];
    const float* fb1       = (const float*)d_in[22];
    const float* fw2       = (const float*)d_in[23];
    const float* fb2       = (const float*)d_in[24];
    const int*   ei        = (const int*)d_in[25];

    char* wsb = (char*)d_ws;
    size_t off = 0;
    auto alloc = [&](size_t bytes) { void* p = wsb + off; off += (bytes + 255) & ~(size_t)255; return p; };

    unsigned short* Qb = (unsigned short*)alloc((size_t)N * HID * 2);
    unsigned short* Kb = (unsigned short*)alloc((size_t)N * HID * 2);
    unsigned short* Vb = (unsigned short*)alloc((size_t)N * HID * 2);
    float* logit_s = (float*)alloc((size_t)E * NH * 4);
    float* aggb    = (float*)alloc((size_t)N * HID * 4);
    int*   cnt     = (int*)alloc((size_t)N * 4);
    int*   starts  = (int*)alloc((size_t)(N + 1) * 4);
    int*   cursor  = (int*)alloc((size_t)N * 4);
    int*   bsum    = (int*)alloc((size_t)NB * 4);
    int*   boff    = (int*)alloc((size_t)NB * 4);
    uint4* esd     = (uint4*)alloc((size_t)E * 16);
    unsigned int*   gvb   = (unsigned int*)alloc((size_t)E * 64 * 4);
    unsigned short* fragW = (unsigned short*)alloc((size_t)18048 * 8 * 2);
    float* outp = (float*)d_out;

    unsigned short* wqkv_f = fragW;
    unsigned short* wo_f   = fragW + (size_t)6144  * 8;
    unsigned short* fw1_f  = fragW + (size_t)8192  * 8;
    unsigned short* fw2_f  = fragW + (size_t)12288 * 8;
    unsigned short* w1ea_f = fragW + (size_t)16384 * 8;
    unsigned short* w2ea_f = fragW + (size_t)16640 * 8;
    unsigned short* w1eg_f = fragW + (size_t)16768 * 8;
    unsigned short* w2eg_f = fragW + (size_t)17024 * 8;

    hipMemsetAsync(cnt, 0, (size_t)N * sizeof(int), stream);

    const int EB = (E + 255) / 256;
    const int NBLK16 = (N + 15) / 16;   // 3125 node blocks (256 threads each)
    k_cvt<<<(18048 + 255) / 256, 256, 0, stream>>>(Wq, Wk, Wv, Wo, fw1, fw2,
                                                   ea_w1, ea_w2, eg_w1, eg_w2, fragW);
    k_ln_qkv_mfma<<<NBLK16, 256, 0, stream>>>(x, ln1_g, ln1_b, wqkv_f, Qb, Kb, Vb);
    k_hist<<<EB, 256, 0, stream>>>(ei, cnt);
    k_bsum<<<NB, 256, 0, stream>>>(cnt, bsum);
    k_scan_b<<<1, 256, 0, stream>>>(bsum, boff);
    k_scan_final<<<NB, 256, 0, stream>>>(cnt, boff, starts, cursor);
    k_scatter<<<EB, 256, 0, stream>>>(ei, cursor, esd);
    // k_edge in 2 chunks (profiling visibility; per-chunk counters verify
    // regalloc health of the native-cast change)
    const int C1 = (EB + 1) / 2;
    const int C2 = EB - C1;
    k_edge<<<C1, 256, 0, stream>>>(0,  edge_attr, esd, Qb, Kb, Vb,
                                   w1ea_f, ea_b1, w2ea_f, ea_b2,
                                   w1eg_f, eg_b1, w2eg_f, eg_b2, logit_s, gvb);
    k_edge<<<C2, 256, 0, stream>>>(C1, edge_attr, esd, Qb, Kb, Vb,
                                   w1ea_f, ea_b1, w2ea_f, ea_b2,
                                   w1eg_f, eg_b1, w2eg_f, eg_b2, logit_s, gvb);
    k_agg2<<<(N + 3) / 4, 256, 0, stream>>>(starts, gvb, logit_s, aggb);
    k_node_out_mfma<<<NBLK16, 256, 0, stream>>>(x, gamma, beta, wo_f, bo, ln2_g, ln2_b,
                                                fw1_f, fb1, fw2_f, fb2, aggb, outp);
}

// Round 12
// 446.093 us; speedup vs baseline: 1.0200x; 1.0200x over previous
//
#include <hip/hip_runtime.h>

constexpr int N   = 50000;
constexpr int E   = 500000;
constexpr int HID = 128;
constexpr int NH  = 8;
constexpr int ED  = 32;
constexpr int EGD = 64;
constexpr int NB  = (N + 255) / 256;

typedef short  bf16x8 __attribute__((ext_vector_type(8)));
typedef float  f32x4  __attribute__((ext_vector_type(4)));

// tanh-form gelu: v * sigmoid(1.5957691*v + 0.0713548*v^3); max |err| vs erf ~3e-4
__device__ __forceinline__ float gelu_f(float v) {
    float u = v * v;
    float a = v * fmaf(u, -0.07135481283f, -1.5957691216f);
    float e = __expf(a);
    return v * __builtin_amdgcn_rcpf(1.f + e);
}
__device__ __forceinline__ float sigm_f(float v) {
    float e = __expf(-v);
    return __builtin_amdgcn_rcpf(1.f + e);
}
// NATIVE bf16 conversion (RTNE) — pure C++ cast, no inline asm (R4 lesson:
// asm in k_edge perturbs regalloc into spill).  R11: cut VALUBusy 39.7->29.0%
// in k_edge (latency-bound, so dur-neutral there) and sped up node kernels.
__device__ __forceinline__ unsigned short f2bf(float f) {
    return __builtin_bit_cast(unsigned short, static_cast<__bf16>(f));
}
__device__ __forceinline__ unsigned int pk2bf(float lo, float hi) {
    return (unsigned int)f2bf(lo) | ((unsigned int)f2bf(hi) << 16);
}
__device__ __forceinline__ float dot2(unsigned int a, unsigned int b) {
    float al = __uint_as_float(a << 16), ah = __uint_as_float(a & 0xffff0000u);
    float bl = __uint_as_float(b << 16), bh = __uint_as_float(b & 0xffff0000u);
    return al * bl + ah * bh;
}

// ---------------------------------------------------------------------------
// Weight conversion: all weight matrices -> bf16 MFMA B-fragment order.
// ---------------------------------------------------------------------------
__global__ __launch_bounds__(256) void k_cvt(
    const float* __restrict__ Wq, const float* __restrict__ Wk,
    const float* __restrict__ Wv, const float* __restrict__ Wo,
    const float* __restrict__ fw1, const float* __restrict__ fw2,
    const float* __restrict__ ea_w1, const float* __restrict__ ea_w2,
    const float* __restrict__ eg_w1, const float* __restrict__ eg_w2,
    unsigned short* __restrict__ dst)
{
    int f = blockIdx.x * 256 + threadIdx.x;
    if (f >= 18048) return;
    const float* W; int KT, srcN, base;
    if      (f < 2048)  { W = Wq;    KT = 4; srcN = 128; base = 0; }
    else if (f < 4096)  { W = Wk;    KT = 4; srcN = 128; base = 2048; }
    else if (f < 6144)  { W = Wv;    KT = 4; srcN = 128; base = 4096; }
    else if (f < 8192)  { W = Wo;    KT = 4; srcN = 128; base = 6144; }
    else if (f < 12288) { W = fw1;   KT = 4; srcN = 256; base = 8192; }
    else if (f < 16384) { W = fw2;   KT = 8; srcN = 128; base = 12288; }
    else if (f < 16640) { W = ea_w1; KT = 1; srcN = 64;  base = 16384; }
    else if (f < 16768) { W = ea_w2; KT = 2; srcN = 8;   base = 16640; }
    else if (f < 17024) { W = eg_w1; KT = 1; srcN = 64;  base = 16768; }
    else                { W = eg_w2; KT = 2; srcN = 128; base = 17024; }
    int fl = f - base, lane = fl & 63, t = fl >> 6;
    int ks = t % KT, nt = t / KT;
    int n  = nt * 16 + (lane & 15);
    int k0 = ks * 32 + (lane >> 4) * 8;
    union { unsigned short u[8]; uint4 v; } o;
#pragma unroll
    for (int j = 0; j < 8; j++)
        o.u[j] = (n < srcN) ? f2bf(W[(size_t)(k0 + j) * srcN + n]) : (unsigned short)0;
    *(uint4*)(dst + (size_t)f * 8) = o.v;
}

// ---------------------------------------------------------------------------
// LN1 + QKV via MFMA -> bf16 Q/K/V.
// COLUMN-SPLIT 4-wave blocks: 16 nodes / 256 threads (R10-verified).
// ---------------------------------------------------------------------------
__global__ __launch_bounds__(256) void k_ln_qkv_mfma(
    const float* __restrict__ x, const float* __restrict__ g1, const float* __restrict__ b1,
    const unsigned short* __restrict__ wqkv,
    unsigned short* __restrict__ Q, unsigned short* __restrict__ K, unsigned short* __restrict__ V)
{
    __shared__ unsigned short xn_lds[16 * 128];   // 4KB
    const int tid = threadIdx.x;
    const int nodeBase = blockIdx.x * 16;         // N % 16 == 0: no bounds checks

    // Phase 0: LN staging — 16 threads per node, each handles 8 cols
    {
        int nl = tid >> 4, q = tid & 15;
        const float4* xp = (const float4*)(x + (size_t)(nodeBase + nl) * HID + q * 8);
        float4 t0 = xp[0], t1 = xp[1];
        float v[8] = {t0.x, t0.y, t0.z, t0.w, t1.x, t1.y, t1.z, t1.w};
        float s = 0.f, ss = 0.f;
#pragma unroll
        for (int i = 0; i < 8; i++) { s += v[i]; ss += v[i] * v[i]; }
        s += __shfl_xor(s, 1); ss += __shfl_xor(ss, 1);
        s += __shfl_xor(s, 2); ss += __shfl_xor(ss, 2);
        s += __shfl_xor(s, 4); ss += __shfl_xor(ss, 4);
        s += __shfl_xor(s, 8); ss += __shfl_xor(ss, 8);
        float mean = s * (1.f / HID);
        float ri = rsqrtf(ss * (1.f / HID) - mean * mean + 1e-5f);
        union { unsigned short u[8]; uint4 v4; } o;
#pragma unroll
        for (int c = 0; c < 8; c++) {
            int col = q * 8 + c;
            o.u[c] = f2bf((v[c] - mean) * ri * g1[col] + b1[col]);
        }
        *(uint4*)&xn_lds[nl * 128 + (q ^ nl) * 8] = o.v4;
    }
    __syncthreads();

    // Phase 1: wave wv computes nt = 6*wv .. 6*wv+5 (swapped operands:
    // C[col][node], thread owns 4 consecutive cols of node lm)
    const int wv = tid >> 6, lane = tid & 63;
    const int lm = lane & 15, kb = lane >> 4, rowq = kb * 4;
    bf16x8 af[4];
#pragma unroll
    for (int ks = 0; ks < 4; ks++)
        af[ks] = *(const bf16x8*)&xn_lds[lm * 128 + ((ks * 4 + kb) ^ lm) * 8];

    const int node = nodeBase + lm;
#pragma unroll
    for (int u = 0; u < 6; u++) {
        int nt = 6 * wv + u;
        f32x4 c = {0.f, 0.f, 0.f, 0.f};
#pragma unroll
        for (int ks = 0; ks < 4; ks++)
            c = __builtin_amdgcn_mfma_f32_16x16x32_bf16(
                    *(const bf16x8*)&wqkv[((size_t)(nt * 4 + ks) * 64 + lane) * 8],
                    af[ks], c, 0, 0, 0);
        unsigned short* O = (nt < 8) ? Q : ((nt < 16) ? K : V);
        uint2 o = make_uint2(pk2bf(c[0], c[1]), pk2bf(c[2], c[3]));
        *(uint2*)(O + (size_t)node * HID + (nt & 7) * 16 + rowq) = o;
    }
}

// ---------------------------------------------------------------------------
// Sorting: histogram -> scan -> scatter (esd = {src, dst, perm, 0} records)
// ---------------------------------------------------------------------------
__global__ __launch_bounds__(256) void k_hist(const int* __restrict__ ei, int* __restrict__ cnt) {
    int e = blockIdx.x * 256 + threadIdx.x;
    if (e < E) atomicAdd(&cnt[ei[E + e]], 1);
}

__global__ __launch_bounds__(256) void k_bsum(const int* __restrict__ cnt, int* __restrict__ bsum) {
    int i = blockIdx.x * 256 + threadIdx.x;
    int v = (i < N) ? cnt[i] : 0;
#pragma unroll
    for (int m = 1; m < 64; m <<= 1) v += __shfl_xor(v, m);
    __shared__ int ws4[4];
    if ((threadIdx.x & 63) == 0) ws4[threadIdx.x >> 6] = v;
    __syncthreads();
    if (threadIdx.x == 0) bsum[blockIdx.x] = ws4[0] + ws4[1] + ws4[2] + ws4[3];
}

__global__ __launch_bounds__(256) void k_scan_b(const int* __restrict__ bsum, int* __restrict__ boff) {
    __shared__ int s[256];
    int t = threadIdx.x;
    int v = (t < NB) ? bsum[t] : 0;
    s[t] = v; __syncthreads();
    for (int off = 1; off < 256; off <<= 1) {
        int add = (t >= off) ? s[t - off] : 0;
        __syncthreads();
        s[t] += add;
        __syncthreads();
    }
    if (t < NB) boff[t] = s[t] - v;
}

__global__ __launch_bounds__(256) void k_scan_final(
    const int* __restrict__ cnt, const int* __restrict__ boff,
    int* __restrict__ starts, int* __restrict__ cursor)
{
    __shared__ int s[256];
    int t = threadIdx.x, i = blockIdx.x * 256 + t;
    int v = (i < N) ? cnt[i] : 0;
    s[t] = v; __syncthreads();
    for (int off = 1; off < 256; off <<= 1) {
        int add = (t >= off) ? s[t - off] : 0;
        __syncthreads();
        s[t] += add;
        __syncthreads();
    }
    int ex = boff[blockIdx.x] + s[t] - v;
    if (i < N) {
        starts[i] = ex;
        cursor[i] = ex;
        if (i == N - 1) starts[N] = ex + v;
    }
}

__global__ __launch_bounds__(256) void k_scatter(
    const int* __restrict__ ei, int* __restrict__ cursor, uint4* __restrict__ esd)
{
    int e = blockIdx.x * 256 + threadIdx.x;
    if (e < E) {
        int src = ei[e], dst = ei[E + e];
        int p = atomicAdd(&cursor[dst], 1);
        esd[p] = make_uint4((unsigned)src, (unsigned)dst, (unsigned)e, 0u);
    }
}

// ---------------------------------------------------------------------------
// Fused edge kernel — SINGLE launch (R11: 2-chunk split cost ~27us in
// inter-launch drain; R5: 3-chunk cost ~15us — never split this kernel).
// REGALLOC DISCIPLINE: plain __launch_bounds__(256), NO waves-arg, NO inline
// asm (R3/R4/R7 regressions).  108 VGPR, zero spill.  Gather-latency-bound
// (R11: cutting 25% of VALU left dur unchanged) at the occupancy ceiling.
// ---------------------------------------------------------------------------
__global__ __launch_bounds__(256) void k_edge(
    const float* __restrict__ edge_attr, const uint4* __restrict__ esd,
    const unsigned short* __restrict__ Qb, const unsigned short* __restrict__ Kb,
    const unsigned short* __restrict__ Vb,
    const unsigned short* __restrict__ w1ea, const float* __restrict__ b1ea,
    const unsigned short* __restrict__ w2ea, const float* __restrict__ b2ea,
    const unsigned short* __restrict__ w1eg, const float* __restrict__ b1eg,
    const unsigned short* __restrict__ w2eg, const float* __restrict__ b2eg,
    float* __restrict__ logit_s, unsigned int* __restrict__ gv)
{
    __shared__ unsigned short ea_lds[256 * 32];      // 16KB: edge_attr bf16, later st16 floats
    __shared__ unsigned short sc_lds[4 * 16 * 64];   // 8KB: per-wave GEMM1->GEMM2 scratch
    __shared__ int perm_lds[256];
    __shared__ int src_lds[256];
    float* st16 = (float*)ea_lds;

    const int tid   = threadIdx.x;
    const int jBase = blockIdx.x * 256;
    const int lane  = tid & 63;
    const int wv    = tid >> 6;
    const int wBase = wv * 64;
    const int lm    = lane & 15;
    const int kb    = lane >> 4;
    const int rowq  = kb * 4;

    const int j  = jBase + tid;
    const int jj = (j < E) ? j : E - 1;
    const uint4 r4 = esd[jj];            // (src, dst, perm, 0)
    {
        perm_lds[tid] = (int)r4.z;
        src_lds[tid]  = (int)r4.x;
    }
    __syncthreads();

    // stage edge_attr[perm[j]] -> bf16 swizzled LDS (packed 8B ds_write)
#pragma unroll
    for (int it = 0; it < 8; it++) {
        int idx = it * 256 + tid;
        int el = idx >> 3, c = (idx & 7) * 4;
        int ge = perm_lds[el];
        float4 v = *(const float4*)(edge_attr + (size_t)ge * ED + c);
        int g = ((c >> 3) ^ (el & 3));
        *(uint2*)&ea_lds[el * 32 + g * 8 + (c & 7)] =
            make_uint2(pk2bf(v.x, v.y), pk2bf(v.z, v.w));
    }
    __syncthreads();
    // everything below is wave-private (own 64 rows of ea_lds / own scratch)

    unsigned short* sc = &sc_lds[wv * 1024];  // [16 edges][64 hid], XOR-swizzled

#pragma unroll 1
    for (int et = 0; et < 4; et++) {
        const int am = wBase + et * 16 + lm;
        const bf16x8 a1 = *(const bf16x8*)&ea_lds[am * 32 + (kb ^ (am & 3)) * 8];

        // ---- ea GEMM1 -> scratch ----
        {
            f32x4 acc[4];
#pragma unroll
            for (int nt = 0; nt < 4; nt++) {
                f32x4 z = {0.f, 0.f, 0.f, 0.f};
                acc[nt] = __builtin_amdgcn_mfma_f32_16x16x32_bf16(
                    a1, *(const bf16x8*)&w1ea[(nt * 64 + lane) * 8], z, 0, 0, 0);
            }
#pragma unroll
            for (int nt = 0; nt < 4; nt++) {
                float bias = b1ea[nt * 16 + lm];
#pragma unroll
                for (int r = 0; r < 4; r++) {
                    int el = rowq + r;
                    int kg = nt * 2 + (lm >> 3);
                    sc[el * 64 + ((kg ^ (el & 7)) * 8) + (lm & 7)] =
                        f2bf(gelu_f(acc[nt][r] + bias));
                }
            }
        }
        // ---- ea GEMM2 -> st16 (same-wave rows; LDS pipe is in-order per wave) ----
        {
            bf16x8 f0 = *(const bf16x8*)&sc[lm * 64 + ((kb ^ (lm & 7)) * 8)];
            bf16x8 f1 = *(const bf16x8*)&sc[lm * 64 + (((4 + kb) ^ (lm & 7)) * 8)];
            float bias = b2ea[lm & 7];
            f32x4 acc = {bias, bias, bias, bias};
            acc = __builtin_amdgcn_mfma_f32_16x16x32_bf16(
                f0, *(const bf16x8*)&w2ea[(0 * 64 + lane) * 8], acc, 0, 0, 0);
            acc = __builtin_amdgcn_mfma_f32_16x16x32_bf16(
                f1, *(const bf16x8*)&w2ea[(1 * 64 + lane) * 8], acc, 0, 0, 0);
            if (lm < 8) {
#pragma unroll
                for (int r = 0; r < 4; r++)
                    st16[(wBase + et * 16 + rowq + r) * 16 + lm] = acc[r];
            }
        }
        // ---- eg GEMM1 (reuse a1) -> scratch (overwrite own rows) ----
        {
            f32x4 acc[4];
#pragma unroll
            for (int nt = 0; nt < 4; nt++) {
                f32x4 z = {0.f, 0.f, 0.f, 0.f};
                acc[nt] = __builtin_amdgcn_mfma_f32_16x16x32_bf16(
                    a1, *(const bf16x8*)&w1eg[(nt * 64 + lane) * 8], z, 0, 0, 0);
            }
#pragma unroll
            for (int nt = 0; nt < 4; nt++) {
                float bias = b1eg[nt * 16 + lm];
#pragma unroll
                for (int r = 0; r < 4; r++) {
                    int el = rowq + r;
                    int kg = nt * 2 + (lm >> 3);
                    sc[el * 64 + ((kg ^ (el & 7)) * 8) + (lm & 7)] =
                        f2bf(gelu_f(acc[nt][r] + bias));
                }
            }
        }
        // ---- eg GEMM2 swapped: C[out_dim][edge]; thread -> edge et*16+lm,
        //      dims mt*16 + kb*4 .. +3 (consecutive) ----
        {
            bf16x8 h0 = *(const bf16x8*)&sc[lm * 64 + ((kb ^ (lm & 7)) * 8)];
            bf16x8 h1 = *(const bf16x8*)&sc[lm * 64 + (((4 + kb) ^ (lm & 7)) * 8)];
            const int e   = jBase + wBase + et * 16 + lm;
            const int src = src_lds[wBase + et * 16 + lm];
            const unsigned short* vrow = Vb + (size_t)src * HID;
            const bool ok = (e < E);
            unsigned int* gvo = gv + (size_t)e * 64 + kb * 2;
#pragma unroll
            for (int mt = 0; mt < 8; mt++) {
                float4 b4 = *(const float4*)&b2eg[mt * 16 + rowq];
                f32x4 acc = {b4.x, b4.y, b4.z, b4.w};
                acc = __builtin_amdgcn_mfma_f32_16x16x32_bf16(
                    *(const bf16x8*)&w2eg[((mt * 2 + 0) * 64 + lane) * 8], h0, acc, 0, 0, 0);
                acc = __builtin_amdgcn_mfma_f32_16x16x32_bf16(
                    *(const bf16x8*)&w2eg[((mt * 2 + 1) * 64 + lane) * 8], h1, acc, 0, 0, 0);
                uint2 vv = *(const uint2*)(vrow + mt * 16 + rowq);
                float w0 = sigm_f(acc[0]) * __uint_as_float(vv.x << 16);
                float w1 = sigm_f(acc[1]) * __uint_as_float(vv.x & 0xffff0000u);
                float w2 = sigm_f(acc[2]) * __uint_as_float(vv.y << 16);
                float w3 = sigm_f(acc[3]) * __uint_as_float(vv.y & 0xffff0000u);
                uint2 o = make_uint2(pk2bf(w0, w1), pk2bf(w2, w3));
                if (ok) *(uint2*)(gvo + mt * 8) = o;
            }
        }
    }

    // ---- QK logit epilogue: store exp(logit) (clamped) for the aggregator ----
    {
        if (j < E) {
            int src = (int)r4.x, dst = (int)r4.y;
            const uint4* qp = (const uint4*)(Qb + (size_t)dst * HID);
            const uint4* kp = (const uint4*)(Kb + (size_t)src * HID);
            float lg[8];
#pragma unroll
            for (int h = 0; h < 8; h++) {
                float dot = 0.f;
#pragma unroll
                for (int t = 0; t < 2; t++) {
                    uint4 q = qp[h * 2 + t], k4 = kp[h * 2 + t];
                    dot += dot2(q.x, k4.x) + dot2(q.y, k4.y) + dot2(q.z, k4.z) + dot2(q.w, k4.w);
                }
                lg[h] = __expf(fminf(st16[tid * 16 + h] + 0.25f * dot, 80.f));
            }
            float4* op = (float4*)(logit_s + (size_t)j * NH);
            op[0] = make_float4(lg[0], lg[1], lg[2], lg[3]);
            op[1] = make_float4(lg[4], lg[5], lg[6], lg[7]);
        }
    }
}

// ---------------------------------------------------------------------------
// Fused segment softmax + attn * gv aggregation, SINGLE PASS.
// logit_s already holds exp(l) (shift-invariant softmax).
// ---------------------------------------------------------------------------
__global__ __launch_bounds__(256) void k_agg2(
    const int* __restrict__ starts, const unsigned int* __restrict__ gv,
    const float* __restrict__ logit_s, float* __restrict__ agg)
{
    int wave = threadIdx.x >> 6, lane = threadIdx.x & 63;
    int dst = blockIdx.x * 4 + wave;
    if (dst >= N) return;
    int s0 = starts[dst], s1 = starts[dst + 1];
    int head = lane >> 3;
    float ssum = 0.f, ax = 0.f, ay = 0.f;
#pragma unroll 4
    for (int j = s0; j < s1; j++) {
        float e = logit_s[(size_t)j * NH + head];
        unsigned int u = gv[(size_t)j * 64 + lane];
        ssum += e;
        ax += e * __uint_as_float(u << 16);
        ay += e * __uint_as_float(u & 0xffff0000u);
    }
    float rs = __builtin_amdgcn_rcpf(ssum + 1e-10f);
    float2* o = (float2*)(agg + (size_t)dst * HID + lane * 2);
    *o = make_float2(ax * rs, ay * rs);
}

// ---------------------------------------------------------------------------
// Node epilogue via MFMA.  COLUMN-SPLIT 4-wave blocks (R10-verified):
// 16 nodes / 256 threads, each wave 1/4 of every GEMM, 4 barriers.
// ---------------------------------------------------------------------------
__global__ __launch_bounds__(256) void k_node_out_mfma(
    const float* __restrict__ x, const float* __restrict__ gamma, const float* __restrict__ beta,
    const unsigned short* __restrict__ wo_f, const float* __restrict__ bo,
    const float* __restrict__ g2, const float* __restrict__ b2,
    const unsigned short* __restrict__ fw1_f, const float* __restrict__ fb1,
    const unsigned short* __restrict__ fw2_f, const float* __restrict__ fb2,
    const float* __restrict__ agg, float* __restrict__ out)
{
    __shared__ unsigned short a_lds[16 * 128];    // 4KB
    __shared__ unsigned short f1_lds[16 * 256];   // 8KB
    __shared__ float2 sums_lds[16][4];            // 512B: per-node per-wave LN partials
    const int tid = threadIdx.x;
    const int nodeBase = blockIdx.x * 16;         // N % 16 == 0

    // Phase 0: stage agg -> a_lds (one uint4 per thread)
    {
        int nl = tid >> 4, q = tid & 15;
        const float4* ap = (const float4*)(agg + (size_t)(nodeBase + nl) * HID + q * 8);
        float4 t0 = ap[0], t1 = ap[1];
        uint4 o = make_uint4(pk2bf(t0.x, t0.y), pk2bf(t0.z, t0.w),
                             pk2bf(t1.x, t1.y), pk2bf(t1.z, t1.w));
        *(uint4*)&a_lds[nl * 128 + (q ^ nl) * 8] = o;
    }
    __syncthreads();

    const int wv = tid >> 6, lane = tid & 63;
    const int lm = lane & 15, kb = lane >> 4, rowq = kb * 4;

    // Phase 1: Wo GEMM — wave wv handles nt = 2*wv + t
    f32x4 xo[2];
    {
        bf16x8 af[4];
#pragma unroll
        for (int ks = 0; ks < 4; ks++)
            af[ks] = *(const bf16x8*)&a_lds[lm * 128 + ((ks * 4 + kb) ^ lm) * 8];
#pragma unroll
        for (int t = 0; t < 2; t++) {
            int nt = 2 * wv + t;
            f32x4 c = {0.f, 0.f, 0.f, 0.f};
#pragma unroll
            for (int ks = 0; ks < 4; ks++)
                c = __builtin_amdgcn_mfma_f32_16x16x32_bf16(
                        af[ks], *(const bf16x8*)&wo_f[((size_t)(nt * 4 + ks) * 64 + lane) * 8],
                        c, 0, 0, 0);
            xo[t] = c;
        }
    }

    // Phase 2: x1 = x + gamma*(xo+bo) + beta for this wave's 32 cols
    float x1v[2][4];
#pragma unroll
    for (int t = 0; t < 2; t++) {
        int col = (2 * wv + t) * 16 + lm;
        float boc = bo[col];
#pragma unroll
        for (int r = 0; r < 4; r++) {
            size_t idx = (size_t)(nodeBase + rowq + r) * HID + col;
            x1v[t][r] = x[idx] + gamma[idx] * (xo[t][r] + boc) + beta[idx];
        }
    }

    // Phase 3: LN partials -> exchange -> full stats
    {
        float s2[4], q2[4];
#pragma unroll
        for (int r = 0; r < 4; r++) {
            s2[r] = x1v[0][r] + x1v[1][r];
            q2[r] = x1v[0][r] * x1v[0][r] + x1v[1][r] * x1v[1][r];
        }
#pragma unroll
        for (int m = 1; m < 16; m <<= 1)
#pragma unroll
            for (int r = 0; r < 4; r++) { s2[r] += __shfl_xor(s2[r], m); q2[r] += __shfl_xor(q2[r], m); }
        if (lm == 0) {
#pragma unroll
            for (int r = 0; r < 4; r++)
                sums_lds[rowq + r][wv] = make_float2(s2[r], q2[r]);
        }
    }
    __syncthreads();
    float mu4[4], ri4[4];
#pragma unroll
    for (int r = 0; r < 4; r++) {
        float2 p0 = sums_lds[rowq + r][0], p1 = sums_lds[rowq + r][1];
        float2 p2 = sums_lds[rowq + r][2], p3 = sums_lds[rowq + r][3];
        float s = p0.x + p1.x + p2.x + p3.x;
        float q = p0.y + p1.y + p2.y + p3.y;
        float mu = s * (1.f / HID);
        mu4[r] = mu;
        ri4[r] = rsqrtf(q * (1.f / HID) - mu * mu + 1e-5f);
    }

    // Phase 4: xn -> a_lds (this wave's 32 cols)
#pragma unroll
    for (int t = 0; t < 2; t++) {
        int col = (2 * wv + t) * 16 + lm;
        float g2c = g2[col], b2c = b2[col];
#pragma unroll
        for (int r = 0; r < 4; r++) {
            float xn = (x1v[t][r] - mu4[r]) * ri4[r] * g2c + b2c;
            int row = rowq + r;
            int g = col >> 3;
            a_lds[row * 128 + (g ^ row) * 8 + (col & 7)] = f2bf(xn);
        }
    }
    __syncthreads();

    // Phase 5: fw1 — wave wv handles nt = 4*wv .. 4*wv+3 -> f1_lds
    {
        bf16x8 af[4];
#pragma unroll
        for (int ks = 0; ks < 4; ks++)
            af[ks] = *(const bf16x8*)&a_lds[lm * 128 + ((ks * 4 + kb) ^ lm) * 8];
#pragma unroll
        for (int u = 0; u < 4; u++) {
            int nt = 4 * wv + u;
            f32x4 c = {0.f, 0.f, 0.f, 0.f};
#pragma unroll
            for (int ks = 0; ks < 4; ks++)
                c = __builtin_amdgcn_mfma_f32_16x16x32_bf16(
                        af[ks], *(const bf16x8*)&fw1_f[((size_t)(nt * 4 + ks) * 64 + lane) * 8],
                        c, 0, 0, 0);
            int col = nt * 16 + lm;
            float fbc = fb1[col];
#pragma unroll
            for (int r = 0; r < 4; r++) {
                int row = rowq + r;
                int g = col >> 3;
                int phys = (g & 16) | ((g ^ row) & 15);
                f1_lds[row * 256 + phys * 8 + (col & 7)] = f2bf(gelu_f(c[r] + fbc));
            }
        }
    }
    __syncthreads();

    // Phase 6: fw2 — wave wv handles nt = 2*wv + t; residual add; store
    {
        bf16x8 af[8];
#pragma unroll
        for (int ks = 0; ks < 8; ks++) {
            int g = ks * 4 + kb;
            int phys = (g & 16) | ((g ^ lm) & 15);
            af[ks] = *(const bf16x8*)&f1_lds[lm * 256 + phys * 8];
        }
#pragma unroll
        for (int t = 0; t < 2; t++) {
            int nt = 2 * wv + t;
            f32x4 c = {0.f, 0.f, 0.f, 0.f};
#pragma unroll
            for (int ks = 0; ks < 8; ks++)
                c = __builtin_amdgcn_mfma_f32_16x16x32_bf16(
                        af[ks], *(const bf16x8*)&fw2_f[((size_t)(nt * 8 + ks) * 64 + lane) * 8],
                        c, 0, 0, 0);
            int col = nt * 16 + lm;
            float fbc = fb2[col];
#pragma unroll
            for (int r = 0; r < 4; r++) {
                int node = nodeBase + rowq + r;
                out[(size_t)node * HID + col] = x1v[t][r] + c[r] + fbc;
            }
        }
    }
}

// ---------------------------------------------------------------------------
extern "C" void kernel_launch(void* const* d_in, const int* in_sizes, int n_in,
                              void* d_out, int out_size, void* d_ws, size_t ws_size,
                              hipStream_t stream)
{
    const float* x         = (const float*)d_in[0];
    const float* edge_attr = (const float*)d_in[1];
    const float* gamma     = (const float*)d_in[2];
    const float* beta      = (const float*)d_in[3];
    const float* Wq        = (const float*)d_in[4];
    const float* Wk        = (const float*)d_in[5];
    const float* Wv        = (const float*)d_in[6];
    const float* Wo        = (const float*)d_in[7];
    const float* bo        = (const float*)d_in[8];
    const float* ea_w1     = (const float*)d_in[9];
    const float* ea_b1     = (const float*)d_in[10];
    const float* ea_w2     = (const float*)d_in[11];
    const float* ea_b2     = (const float*)d_in[12];
    const float* eg_w1     = (const float*)d_in[13];
    const float* eg_b1     = (const float*)d_in[14];
    const float* eg_w2     = (const float*)d_in[15];
    const float* eg_b2     = (const float*)d_in[16];
    const float* ln1_g     = (const float*)d_in[17];
    const float* ln1_b     = (const float*)d_in[18];
    const float* ln2_g     = (const float*)d_in[19];
    const float* ln2_b     = (const float*)d_in[20];
    const float* fw1       = (const float*)d_in[21];
    const float* fb1       = (const float*)d_in[22];
    const float* fw2       = (const float*)d_in[23];
    const float* fb2       = (const float*)d_in[24];
    const int*   ei        = (const int*)d_in[25];

    char* wsb = (char*)d_ws;
    size_t off = 0;
    auto alloc = [&](size_t bytes) { void* p = wsb + off; off += (bytes + 255) & ~(size_t)255; return p; };

    unsigned short* Qb = (unsigned short*)alloc((size_t)N * HID * 2);
    unsigned short* Kb = (unsigned short*)alloc((size_t)N * HID * 2);
    unsigned short* Vb = (unsigned short*)alloc((size_t)N * HID * 2);
    float* logit_s = (float*)alloc((size_t)E * NH * 4);
    float* aggb    = (float*)alloc((size_t)N * HID * 4);
    int*   cnt     = (int*)alloc((size_t)N * 4);
    int*   starts  = (int*)alloc((size_t)(N + 1) * 4);
    int*   cursor  = (int*)alloc((size_t)N * 4);
    int*   bsum    = (int*)alloc((size_t)NB * 4);
    int*   boff    = (int*)alloc((size_t)NB * 4);
    uint4* esd     = (uint4*)alloc((size_t)E * 16);
    unsigned int*   gvb   = (unsigned int*)alloc((size_t)E * 64 * 4);
    unsigned short* fragW = (unsigned short*)alloc((size_t)18048 * 8 * 2);
    float* outp = (float*)d_out;

    unsigned short* wqkv_f = fragW;
    unsigned short* wo_f   = fragW + (size_t)6144  * 8;
    unsigned short* fw1_f  = fragW + (size_t)8192  * 8;
    unsigned short* fw2_f  = fragW + (size_t)12288 * 8;
    unsigned short* w1ea_f = fragW + (size_t)16384 * 8;
    unsigned short* w2ea_f = fragW + (size_t)16640 * 8;
    unsigned short* w1eg_f = fragW + (size_t)16768 * 8;
    unsigned short* w2eg_f = fragW + (size_t)17024 * 8;

    hipMemsetAsync(cnt, 0, (size_t)N * sizeof(int), stream);

    const int EB = (E + 255) / 256;
    const int NBLK16 = (N + 15) / 16;   // 3125 node blocks (256 threads each)
    k_cvt<<<(18048 + 255) / 256, 256, 0, stream>>>(Wq, Wk, Wv, Wo, fw1, fw2,
                                                   ea_w1, ea_w2, eg_w1, eg_w2, fragW);
    k_ln_qkv_mfma<<<NBLK16, 256, 0, stream>>>(x, ln1_g, ln1_b, wqkv_f, Qb, Kb, Vb);
    k_hist<<<EB, 256, 0, stream>>>(ei, cnt);
    k_bsum<<<NB, 256, 0, stream>>>(cnt, bsum);
    k_scan_b<<<1, 256, 0, stream>>>(bsum, boff);
    k_scan_final<<<NB, 256, 0, stream>>>(cnt, boff, starts, cursor);
    k_scatter<<<EB, 256, 0, stream>>>(ei, cursor, esd);
    k_edge<<<EB, 256, 0, stream>>>(edge_attr, esd, Qb, Kb, Vb,
                                   w1ea_f, ea_b1, w2ea_f, ea_b2,
                                   w1eg_f, eg_b1, w2eg_f, eg_b2,
                                   logit_s, gvb);
    k_agg2<<<(N + 3) / 4, 256, 0, stream>>>(starts, gvb, logit_s, aggb);
    k_node_out_mfma<<<NBLK16, 256, 0, stream>>>(x, gamma, beta, wo_f, bo, ln2_g, ln2_b,
                                                fw1_f, fb1, fw2_f, fb2, aggb, outp);
}